// Round 1
// baseline (597.934 us; speedup 1.0000x reference)
//
#include <hip/hip_runtime.h>
#include <hip/hip_bf16.h>
#include <math.h>

#define C_DIM 256
#define H_HEADS 8
#define B_GRAPHS 2048
#define NPG 128
#define N_NODES (B_GRAPHS * NPG)   // 262144
#define EPS 1e-5f
#define SCALE_ATT 0.17677669529663687f   // 1/sqrt(32)

typedef short bf16x8 __attribute__((ext_vector_type(8)));
typedef float f32x4 __attribute__((ext_vector_type(4)));

__device__ __forceinline__ unsigned short f2bf(float f) {
    __hip_bfloat16 h = __float2bfloat16(f);
    union { __hip_bfloat16 h; unsigned short u; } cv; cv.h = h; return cv.u;
}
__device__ __forceinline__ float bf2f(unsigned short u) {
    union { unsigned int i; float f; } v; v.i = ((unsigned int)u) << 16; return v.f;
}

// ---------------- prepA: W1 -> bf16 (blocks 0..255) + prep1 (block 256) ----------------
// qh = rowsum(Wq)+bq ; wk_eff[head,c'] = scale * sum_d Wk[head*32+d,c']*qh[head*32+d]
// wor[j] = sum_j2 Wo[j2,j]*Wr[j2]
__global__ __launch_bounds__(256) void prepA_kernel(
    const float* __restrict__ W1, unsigned short* __restrict__ W1bf,
    const float* __restrict__ Wq, const float* __restrict__ bq,
    const float* __restrict__ Wk, const float* __restrict__ Wo,
    const float* __restrict__ Wr,
    float* __restrict__ wk_eff, float* __restrict__ wor)
{
    __shared__ float qhS[256];
    __shared__ float WrS[256];
    const int t = threadIdx.x;
    if (blockIdx.x < 256) {
        int i = blockIdx.x * 256 + t;
        W1bf[i] = f2bf(W1[i]);
        return;
    }
    {
        float s = bq[t];
        const float* row = Wq + (size_t)t * 256;
        for (int c = 0; c < 256; c += 4) {
            float4 v = *(const float4*)&row[c];
            s += v.x + v.y + v.z + v.w;
        }
        qhS[t] = s;
        WrS[t] = Wr[t];
    }
    __syncthreads();
    for (int head = 0; head < 8; ++head) {
        float acc = 0.f;
        #pragma unroll 4
        for (int d = 0; d < 32; ++d)
            acc = fmaf(Wk[(size_t)(head * 32 + d) * 256 + t], qhS[head * 32 + d], acc);
        wk_eff[head * 256 + t] = acc * SCALE_ATT;
    }
    {
        float acc = 0.f;
        for (int j2 = 0; j2 < 256; ++j2)
            acc = fmaf(Wo[(size_t)j2 * 256 + t], WrS[j2], acc);
        wor[t] = acc;
    }
}

// ---------------- GEMM (blocks 0..2047) + per-head fold (blocks 2048..2055) ----------------
// GEMM: h1[n][c] = sum_k x[n,k] * W1[c,k]   (b1 cancels through LN)
// A = W1 rows (M = c), B = x node rows (N = nodes).
// D mapping: lane holds c = mt*16 + kg*4 + r  (4 consecutive c!), node = w*32 + (0|16) + l15
//  -> row-major ushort4 stores. Stats: butterfly over l15 (nodes) -> LDS ds_add -> global atomic.
__global__ __launch_bounds__(256) void gemm_kernel(
    const float* __restrict__ x, const unsigned short* __restrict__ W1bf,
    unsigned short* __restrict__ h1,
    float* __restrict__ psum, float* __restrict__ psum2,
    const float* __restrict__ W2, const float* __restrict__ Wv,
    const float* __restrict__ wk_eff, const float* __restrict__ wor,
    const float* __restrict__ b2, const float* __restrict__ bv,
    const float* __restrict__ bo, const float* __restrict__ Wr,
    const float* __restrict__ br,
    unsigned short* __restrict__ WBg, float* __restrict__ c0)
{
    __shared__ unsigned short Wlds[256 * 40];   // 20.5 KB
    __shared__ unsigned short Xlds[128 * 40];   // 10 KB
    __shared__ float red1[256], red2[256];      // 2 KB
    __shared__ float worS[32];
    const int t = threadIdx.x;

    if (blockIdx.x >= 2048) {
        // ---- per-head fold (old prep2+prep3+prep4) ----
        const int head = blockIdx.x - 2048;
        float* wkS = red1;
        float* vS  = red2;
        wkS[t] = wk_eff[head * 256 + t];
        if (t < 32) worS[t] = wor[head * 32 + t];
        __syncthreads();
        float acc = 0.f;
        #pragma unroll 4
        for (int cp = 0; cp < 256; ++cp)
            acc = fmaf(W2[(size_t)cp * 256 + t], wkS[cp], acc);
        WBg[head * 256 + t] = f2bf(acc);          // wfold row (logits weights)
        float accv = 0.f;
        #pragma unroll 4
        for (int d = 0; d < 32; ++d)
            accv = fmaf(Wv[(size_t)(head * 32 + d) * 256 + t], worS[d], accv);
        vS[t] = accv;
        __syncthreads();
        float accg = 0.f;
        #pragma unroll 4
        for (int cp = 0; cp < 256; ++cp)
            accg = fmaf(W2[(size_t)cp * 256 + t], vS[cp], accg);
        WBg[(8 + head) * 256 + t] = f2bf(accg);   // G row (gdot weights)
        // c0 contributions: sum_t b2*V_h ; head 0 adds sum bv*wor + bo*Wr + br
        float part = b2[t] * accv;
        if (head == 0) {
            part += bv[t] * wor[t] + bo[t] * Wr[t];
            if (t == 0) part += br[0];
        }
        #pragma unroll
        for (int s = 1; s < 64; s <<= 1) part += __shfl_xor(part, s);
        if ((t & 63) == 0) atomicAdd(c0, part);
        return;
    }

    const int lane = t & 63, w = t >> 6;
    const int l15 = lane & 15, kg = lane >> 4;
    const size_t n0 = (size_t)blockIdx.x * 128;

    red1[t] = 0.f;
    red2[t] = 0.f;

    f32x4 acc0[16], acc1[16];
    #pragma unroll
    for (int mt = 0; mt < 16; ++mt) {
        acc0[mt] = (f32x4){0.f, 0.f, 0.f, 0.f};
        acc1[mt] = (f32x4){0.f, 0.f, 0.f, 0.f};
    }

    for (int kk = 0; kk < 8; ++kk) {
        if (kk) __syncthreads();
        #pragma unroll
        for (int p = 0; p < 4; ++p) {
            int i = p * 256 + t;
            {   // X: x chunk 128 rows x 32 k fp32 -> bf16 LDS
                int row = i >> 3, kq = i & 7;
                float4 v = *(const float4*)&x[(n0 + row) * 256 + kk * 32 + kq * 4];
                ushort4 u;
                u.x = f2bf(v.x); u.y = f2bf(v.y); u.z = f2bf(v.z); u.w = f2bf(v.w);
                *(ushort4*)&Xlds[row * 40 + kq * 4] = u;
            }
            {   // W: W1bf chunk 256 rows x 32 k
                int row = i >> 2, seg = i & 3;
                bf16x8 bv8 = *(const bf16x8*)&W1bf[(size_t)row * 256 + kk * 32 + seg * 8];
                *(bf16x8*)&Wlds[row * 40 + seg * 8] = bv8;
            }
        }
        __syncthreads();
        bf16x8 b0 = *(const bf16x8*)&Xlds[(w * 32 + l15) * 40 + kg * 8];
        bf16x8 b1 = *(const bf16x8*)&Xlds[(w * 32 + 16 + l15) * 40 + kg * 8];
        #pragma unroll
        for (int mt = 0; mt < 16; ++mt) {
            bf16x8 a = *(const bf16x8*)&Wlds[(mt * 16 + l15) * 40 + kg * 8];
            acc0[mt] = __builtin_amdgcn_mfma_f32_16x16x32_bf16(a, b0, acc0[mt], 0, 0, 0);
            acc1[mt] = __builtin_amdgcn_mfma_f32_16x16x32_bf16(a, b1, acc1[mt], 0, 0, 0);
        }
    }

    // epilogue: row-major packed stores + channel stats
    const size_t rb0 = (n0 + w * 32 + l15) * 256;
    const size_t rb1 = rb0 + 16 * 256;
    #pragma unroll
    for (int mt = 0; mt < 16; ++mt) {
        f32x4 a0 = acc0[mt], a1 = acc1[mt];
        ushort4 u0, u1;
        u0.x = f2bf(a0[0]); u0.y = f2bf(a0[1]); u0.z = f2bf(a0[2]); u0.w = f2bf(a0[3]);
        u1.x = f2bf(a1[0]); u1.y = f2bf(a1[1]); u1.z = f2bf(a1[2]); u1.w = f2bf(a1[3]);
        *(ushort4*)&h1[rb0 + mt * 16 + kg * 4] = u0;
        *(ushort4*)&h1[rb1 + mt * 16 + kg * 4] = u1;
        float s1v[4], s2v[4];
        #pragma unroll
        for (int r = 0; r < 4; ++r) {
            s1v[r] = a0[r] + a1[r];
            s2v[r] = a0[r] * a0[r] + a1[r] * a1[r];
        }
        #pragma unroll
        for (int r = 0; r < 4; ++r) {
            #pragma unroll
            for (int s = 1; s < 16; s <<= 1) {
                s1v[r] += __shfl_xor(s1v[r], s);
                s2v[r] += __shfl_xor(s2v[r], s);
            }
        }
        if (l15 == 0) {
            #pragma unroll
            for (int r = 0; r < 4; ++r) {
                atomicAdd(&red1[mt * 16 + kg * 4 + r], s1v[r]);
                atomicAdd(&red2[mt * 16 + kg * 4 + r], s2v[r]);
            }
        }
    }
    __syncthreads();
    atomicAdd(&psum[t], red1[t]);
    atomicAdd(&psum2[t], red2[t]);
}

// ---------------- fused per-graph kernel (LDS-free LN path) ----------------
// A = WB rows (16 j), B = LN+ReLU(h1) node rows, built in registers from row-major h1.
// D: lane holds j = kg*4+r, node = w*32 + (0|16) + l15.
__global__ __launch_bounds__(256) void fused_kernel(
    const unsigned short* __restrict__ h1,
    const float* __restrict__ psum, const float* __restrict__ psum2,
    const float* __restrict__ gamma, const float* __restrict__ beta,
    const unsigned short* __restrict__ WBg,
    const float* __restrict__ c0_g, float* __restrict__ out)
{
    __shared__ float scS[256], shS[256];
    __shared__ float LG[128 * 17];
    __shared__ float redH[8];

    const int t = threadIdx.x;
    const int g = blockIdx.x;
    const int lane = t & 63, w = t >> 6;
    const int l15 = lane & 15, kg = lane >> 4;

    {   // finalize LN stats per block (1 KB L2-resident reads; replaces stats_kernel)
        const float invN = 1.0f / (float)N_NODES;
        float S = psum[t], S2 = psum2[t];
        float mu = S * invN;
        float var = S2 * invN - mu * mu;
        float rstd = rsqrtf(var + EPS);
        float gmr = gamma[t] * rstd;
        scS[t] = gmr;
        shS[t] = beta[t] - mu * gmr;
    }
    // WB fragments held in registers (8 KB, L2-resident)
    bf16x8 af[8];
    #pragma unroll
    for (int kt = 0; kt < 8; ++kt)
        af[kt] = *(const bf16x8*)&WBg[l15 * 256 + kt * 32 + kg * 8];
    __syncthreads();

    const size_t base0 = ((size_t)g * 128 + w * 32 + l15) * 256;
    const size_t base1 = base0 + 16 * 256;
    f32x4 acc0 = {0.f, 0.f, 0.f, 0.f}, acc1 = {0.f, 0.f, 0.f, 0.f};
    #pragma unroll
    for (int kt = 0; kt < 8; ++kt) {
        const int cc = kt * 32 + kg * 8;
        bf16x8 h0 = *(const bf16x8*)&h1[base0 + cc];
        bf16x8 h1v = *(const bf16x8*)&h1[base1 + cc];
        f32x4 scA = *(const f32x4*)&scS[cc];
        f32x4 scB = *(const f32x4*)&scS[cc + 4];
        f32x4 shA = *(const f32x4*)&shS[cc];
        f32x4 shB = *(const f32x4*)&shS[cc + 4];
        bf16x8 b0, b1;
        #pragma unroll
        for (int e = 0; e < 4; ++e) {
            b0[e]     = (short)f2bf(fmaxf(fmaf(bf2f((unsigned short)h0[e]),      scA[e], shA[e]), 0.f));
            b0[e + 4] = (short)f2bf(fmaxf(fmaf(bf2f((unsigned short)h0[e + 4]),  scB[e], shB[e]), 0.f));
            b1[e]     = (short)f2bf(fmaxf(fmaf(bf2f((unsigned short)h1v[e]),     scA[e], shA[e]), 0.f));
            b1[e + 4] = (short)f2bf(fmaxf(fmaf(bf2f((unsigned short)h1v[e + 4]), scB[e], shB[e]), 0.f));
        }
        acc0 = __builtin_amdgcn_mfma_f32_16x16x32_bf16(af[kt], b0, acc0, 0, 0, 0);
        acc1 = __builtin_amdgcn_mfma_f32_16x16x32_bf16(af[kt], b1, acc1, 0, 0, 0);
    }
    #pragma unroll
    for (int r = 0; r < 4; ++r) {
        LG[(w * 32 + l15) * 17 + kg * 4 + r]      = acc0[r];
        LG[(w * 32 + 16 + l15) * 17 + kg * 4 + r] = acc1[r];
    }
    __syncthreads();

    // per-head: softmax-weighted gdot (bfold cancels; no attn materialization)
    {
        const int h = t >> 5, j = t & 31;
        float l[4], gv[4];
        #pragma unroll
        for (int q = 0; q < 4; ++q) {
            int n = j + q * 32;
            l[q]  = LG[n * 17 + h];
            gv[q] = LG[n * 17 + 8 + h];
        }
        float m = fmaxf(fmaxf(l[0], l[1]), fmaxf(l[2], l[3]));
        for (int s = 16; s > 0; s >>= 1) m = fmaxf(m, __shfl_xor(m, s, 32));
        float sp = 0.f, sg = 0.f;
        #pragma unroll
        for (int q = 0; q < 4; ++q) {
            float p = expf(l[q] - m);
            sp += p;
            sg = fmaf(p, gv[q], sg);
        }
        for (int s = 16; s > 0; s >>= 1) {
            sp += __shfl_xor(sp, s, 32);
            sg += __shfl_xor(sg, s, 32);
        }
        if (j == 0) redH[h] = sg / sp;
    }
    __syncthreads();
    if (t == 0) {
        float r = c0_g[0];
        #pragma unroll
        for (int h = 0; h < 8; ++h) r += redH[h];
        out[g] = tanhf(r);
    }
}

// ---------------- launch ----------------
// ws: h1 (N*256 u16) | W1bf (65536 u16) | WBg (4096 u16) | floats:
//     wk_eff[2048] | wor[256] | psum[256] | psum2[256] | c0[1]
extern "C" void kernel_launch(void* const* d_in, const int* in_sizes, int n_in,
                              void* d_out, int out_size, void* d_ws, size_t ws_size,
                              hipStream_t stream)
{
    (void)in_sizes; (void)n_in; (void)out_size; (void)ws_size;
    const float* x     = (const float*)d_in[0];
    const float* W1    = (const float*)d_in[3];
    // d_in[4] = b1: cancels exactly through the batch-mean subtraction in LN
    const float* gamma = (const float*)d_in[5];
    const float* beta  = (const float*)d_in[6];
    const float* W2    = (const float*)d_in[7];
    const float* b2    = (const float*)d_in[8];
    const float* Wq    = (const float*)d_in[9];
    const float* bq    = (const float*)d_in[10];
    const float* Wk    = (const float*)d_in[11];
    const float* Wv    = (const float*)d_in[13];
    const float* bv    = (const float*)d_in[14];
    const float* Wo    = (const float*)d_in[15];
    const float* bo    = (const float*)d_in[16];
    const float* Wr    = (const float*)d_in[17];
    const float* br    = (const float*)d_in[18];

    unsigned short* h1   = (unsigned short*)d_ws;
    unsigned short* W1bf = h1 + (size_t)N_NODES * 256;
    unsigned short* WBg  = W1bf + 65536;
    float* fbase = (float*)(WBg + 4096);

    float* wk_eff = fbase;
    float* wor    = fbase + 2048;
    float* psum   = fbase + 2304;
    float* psum2  = fbase + 2560;
    float* c0     = fbase + 2816;

    hipMemsetAsync((void*)psum, 0, 513 * sizeof(float), stream);

    hipLaunchKernelGGL(prepA_kernel, dim3(257), dim3(256), 0, stream,
                       W1, W1bf, Wq, bq, Wk, Wo, Wr, wk_eff, wor);
    hipLaunchKernelGGL(gemm_kernel, dim3(2056), dim3(256), 0, stream,
                       x, W1bf, h1, psum, psum2,
                       W2, Wv, wk_eff, wor, b2, bv, bo, Wr, br, WBg, c0);
    hipLaunchKernelGGL(fused_kernel, dim3(B_GRAPHS), dim3(256), 0, stream,
                       h1, psum, psum2, gamma, beta, WBg, c0, (float*)d_out);
}